// Round 3
// baseline (1014.695 us; speedup 1.0000x reference)
//
#include <hip/hip_runtime.h>
#include <stdint.h>

#define NPTS 120000

typedef __attribute__((ext_vector_type(8))) short bf16x8;   // 8 bf16 = 4 VGPR
typedef __attribute__((ext_vector_type(4))) float f32x4;    // MFMA C/D

__device__ __forceinline__ uint16_t f2b(float f) {
    union { float f; uint32_t i; } v; v.f = f;
    uint32_t x = v.i;
    return (uint16_t)((x + 0x7fffu + ((x >> 16) & 1u)) >> 16);   // RNE
}
__device__ __forceinline__ float b2f(uint16_t u) {
    union { uint32_t i; float f; } v; v.i = ((uint32_t)u) << 16; return v.f;
}
__device__ __forceinline__ bf16x8 cvt8(f32x4 a, f32x4 b) {
    bf16x8 t;
    t[0] = (short)f2b(a[0]); t[1] = (short)f2b(a[1]);
    t[2] = (short)f2b(a[2]); t[3] = (short)f2b(a[3]);
    t[4] = (short)f2b(b[0]); t[5] = (short)f2b(b[1]);
    t[6] = (short)f2b(b[2]); t[7] = (short)f2b(b[3]);
    return t;
}
#define MFMA(a, b, c) __builtin_amdgcn_mfma_f32_16x16x32_bf16((a), (b), (c), 0, 0, 0)

// ======================================================================
// Weight swizzle (validated): f32 [K][N] -> bf16 B-frag order,
// flat ((nt*(K/32)+kc)*64 + l)*8 + j. Also zeroes T1 sentinel row NPTS.
// ======================================================================
__global__ __launch_bounds__(256) void k_swz(
    const float* __restrict__ W1s, const float* __restrict__ Wks,
    const float* __restrict__ W2s, const float* __restrict__ Wf,
    uint16_t* __restrict__ Z, uint16_t* __restrict__ T1z)
{
    if (blockIdx.x == 0 && threadIdx.x < 64)
        T1z[(size_t)NPTS * 64 + threadIdx.x] = 0;   // sentinel zero-row
    int idx = blockIdx.x * 256 + threadIdx.x;
    if (idx >= 778240) return;
    const float* src; int K, N, r;
    if (idx < 49152)       { src = W1s + (idx / 8192) * 8192;           K = 128; N = 64;  r = idx & 8191; }
    else if (idx < 712704) { int t = idx - 49152;  src = Wks + (t >> 12) * 4096; K = 64;  N = 64;  r = t & 4095; }
    else if (idx < 761856) { int t = idx - 712704; src = W2s + (t / 8192) * 8192; K = 64;  N = 128; r = t & 8191; }
    else                   { src = Wf; K = 128; N = 128; r = idx - 761856; }
    int j  = r & 7;
    int l  = (r >> 3) & 63;
    int t2 = r >> 9;
    int KC = K >> 5;
    int kc = t2 % KC;
    int nt = t2 / KC;
    int k  = kc * 32 + (l >> 4) * 8 + j;
    int n  = nt * 16 + (l & 15);
    Z[idx] = f2b(src[k * N + n]);
}

// ======================================================================
// T[p][c] = relu(H[p][:] @ W1[:,c]),  K=128, N=64.  (unchanged)
// ======================================================================
__global__ __launch_bounds__(256) void k_gemm1(
    const float* __restrict__ H, const uint16_t* __restrict__ Wz,
    uint16_t* __restrict__ T)
{
    const int tid = threadIdx.x;
    const int wv = tid >> 6, ln = tid & 63;
    const int m = ln & 15, part = ln >> 4;
    const long rb = (long)blockIdx.x * 64 + wv * 16;

    bf16x8 a[4];
    const float* hrow = H + (rb + m) * 128 + part * 8;
    #pragma unroll
    for (int kc = 0; kc < 4; ++kc) {
        f32x4 h0 = *reinterpret_cast<const f32x4*>(hrow + kc * 32);
        f32x4 h1 = *reinterpret_cast<const f32x4*>(hrow + kc * 32 + 4);
        a[kc] = cvt8(h0, h1);
    }
    #pragma unroll
    for (int nt = 0; nt < 4; ++nt) {
        f32x4 acc = (f32x4)(0.0f);
        #pragma unroll
        for (int kc = 0; kc < 4; ++kc) {
            bf16x8 b = *reinterpret_cast<const bf16x8*>(Wz + ((nt * 4 + kc) * 64 + ln) * 8);
            acc = MFMA(a[kc], b, acc);
        }
        #pragma unroll
        for (int r = 0; r < 4; ++r) {
            float v = acc[r] > 0.f ? acc[r] : 0.f;
            T[(rb + part * 4 + r) * 64 + nt * 16 + m] = f2b(v);
        }
    }
}

// ======================================================================
// Fused conv27 + gemm2.
// ROUND-3: TLP instead of ILP. R2 post-mortem: VGPR stayed 92 -> the
// allocator re-materialized the pinned prefetches; sched_barrier only
// serialized the schedule (99 -> 119 us). The kernel is gather-latency
// bound (T rows scattered, ~L3-hit 500cyc) with only 2.4 waves/SIMD of
// cover. Fix: 32 rows/wave, 2-wave (128-thr) blocks, 1875 blocks ->
// 3750 waves = 14.6 waves/CU (~3.7/SIMD), 1.5x TLP. acc shrinks 48->32
// VGPRs so the depth-1 A/B ping-pong has a chance to survive under
// __launch_bounds__(128,4) (VGPR<=128 -> 4 waves/SIMD, = grid cap).
// All sched_barriers removed (proven harmful R2). The 2 waves of a
// block stream the same B panel -> L1 absorbs the duplicate fetch.
// LDS: snbr 6912 + sc2 10240 = 17152 B. In-place safe (block owns its
// 64 rows; epilogue same-lane read-then-write).
// ======================================================================
__global__ __launch_bounds__(128, 4) void k_convg2(
    const uint16_t* __restrict__ T,     // [(NPTS+1)][64] bf16, row NPTS = 0
    const uint16_t* __restrict__ Wkz,   // 27 swizzled 64x64 (4096 each)
    const uint16_t* __restrict__ W2z,   // swizzled 64x128
    const float* Hin,                   // may alias Hout
    const int* __restrict__ nbr,
    float* HoutF, uint16_t* __restrict__ HoutB, int out_bf16)
{
    __shared__ int snbr[64 * 27];                        // 6912 B, [lp][kk], pre-scaled <<6
    __shared__ __align__(16) uint16_t sc2[2][32 * 80];   // 10240 B (per-wave halves)
    const int tid = threadIdx.x;
    const int wv = tid >> 6, ln = tid & 63;              // wv 0..1
    const int mrow = ln & 15, part = ln >> 4;
    const int pc8 = part * 8;
    const long bb = (long)blockIdx.x * 64;
    const long wb0 = bb + wv * 32;                       // this wave's first row

    // snbr[lp*27+kk] = elem offset (row*64) of neighbor, sentinel -> NPTS
    const int* nb = nbr + bb * 27;
    for (int i = tid; i < 1728; i += 128) {
        int n = nb[i];
        snbr[i] = ((n < 0) ? NPTS : n) << 6;
    }
    __syncthreads();

    f32x4 acc[2][4];
    #pragma unroll
    for (int mm = 0; mm < 2; ++mm)
        #pragma unroll
        for (int nt = 0; nt < 4; ++nt) acc[mm][nt] = (f32x4)(0.0f);

    // depth-1 ping-pong, fully-named buffers (static indexing only)
    bf16x8 p0A[2][2], p0B[8];
    bf16x8 p1A[2][2], p1B[8];

#define LOAD(buf, kk)                                                            \
    {                                                                            \
        _Pragma("unroll")                                                        \
        for (int mm = 0; mm < 2; ++mm) {                                         \
            long r0 = (long)snbr[(wv * 32 + mm * 16 + mrow) * 27 + (kk)];        \
            const uint16_t* src = T + r0 + pc8;                                  \
            buf##A[mm][0] = *reinterpret_cast<const bf16x8*>(src);               \
            buf##A[mm][1] = *reinterpret_cast<const bf16x8*>(src + 32);          \
        }                                                                        \
        const uint16_t* wb = Wkz + (kk) * 4096 + ln * 8;                         \
        _Pragma("unroll")                                                        \
        for (int i = 0; i < 8; ++i)                                              \
            buf##B[i] = *reinterpret_cast<const bf16x8*>(wb + i * 512);          \
    }

#define TAP(buf)                                                                 \
    {                                                                            \
        _Pragma("unroll")                                                        \
        for (int nt = 0; nt < 4; ++nt) {                                         \
            _Pragma("unroll")                                                    \
            for (int mm = 0; mm < 2; ++mm) {                                     \
                acc[mm][nt] = MFMA(buf##A[mm][0], buf##B[nt * 2 + 0], acc[mm][nt]); \
                acc[mm][nt] = MFMA(buf##A[mm][1], buf##B[nt * 2 + 1], acc[mm][nt]); \
            }                                                                    \
        }                                                                        \
    }

    LOAD(p0, 0);
    LOAD(p1, 1);
    #pragma unroll 1
    for (int k = 0; k < 24; k += 2) {   // taps 0..23
        TAP(p0); LOAD(p0, k + 2);       // prefetch even tap k+2 (<=24)
        TAP(p1); LOAD(p1, k + 3);       // prefetch odd  tap k+3 (<=25)
    }
    TAP(p0); LOAD(p0, 26);              // tap 24, prefetch 26
    TAP(p1);                            // tap 25
    TAP(p0);                            // tap 26
#undef LOAD
#undef TAP

    // transpose: acc (C-layout) -> sc2 (relu, bf16), stride 80 shorts
    uint16_t* scw = sc2[wv];
    #pragma unroll
    for (int mm = 0; mm < 2; ++mm)
        #pragma unroll
        for (int nt = 0; nt < 4; ++nt)
            #pragma unroll
            for (int r = 0; r < 4; ++r) {
                float v = acc[mm][nt][r];
                v = v > 0.f ? v : 0.f;
                scw[(mm * 16 + part * 4 + r) * 80 + nt * 16 + mrow] = f2b(v);
            }
    __builtin_amdgcn_wave_barrier();    // same-wave producer/consumer fence

    bf16x8 a2[2][2];
    #pragma unroll
    for (int mm = 0; mm < 2; ++mm) {
        const uint16_t* crow = scw + (mm * 16 + mrow) * 80;
        a2[mm][0] = *reinterpret_cast<const bf16x8*>(crow + pc8);
        a2[mm][1] = *reinterpret_cast<const bf16x8*>(crow + 32 + pc8);
    }

    // gemm2: K=64, N=128 (8 n-tiles), per-tile epilogue keeps VGPR low
    #pragma unroll 2
    for (int nt = 0; nt < 8; ++nt) {
        bf16x8 b0 = *reinterpret_cast<const bf16x8*>(W2z + ((nt * 2 + 0) * 64 + ln) * 8);
        bf16x8 b1 = *reinterpret_cast<const bf16x8*>(W2z + ((nt * 2 + 1) * 64 + ln) * 8);
        f32x4 c[2];
        #pragma unroll
        for (int mm = 0; mm < 2; ++mm) {
            c[mm] = (f32x4)(0.0f);
            c[mm] = MFMA(a2[mm][0], b0, c[mm]);
            c[mm] = MFMA(a2[mm][1], b1, c[mm]);
        }
        const int col = nt * 16 + mrow;
        if (out_bf16) {
            #pragma unroll
            for (int mm = 0; mm < 2; ++mm)
                #pragma unroll
                for (int r = 0; r < 4; ++r) {
                    long p = wb0 + mm * 16 + part * 4 + r;
                    float v = c[mm][r] + Hin[p * 128 + col];
                    v = v > 0.f ? v : 0.f;
                    HoutB[p * 128 + col] = f2b(v);
                }
        } else {
            #pragma unroll
            for (int mm = 0; mm < 2; ++mm)
                #pragma unroll
                for (int r = 0; r < 4; ++r) {
                    long p = wb0 + mm * 16 + part * 4 + r;
                    float v = c[mm][r] + Hin[p * 128 + col];
                    HoutF[p * 128 + col] = v > 0.f ? v : 0.f;
                }
        }
    }
}

// ======================================================================
// Out[p][c] = A[p][c] * sigmoid( B[p][:] @ Wf[:,c] ) + X[p][c]
// (unchanged; in-place safe Out==B)
// ======================================================================
__global__ __launch_bounds__(256) void k_final(
    const float* B, const uint16_t* __restrict__ Wfz,
    const uint16_t* __restrict__ A16, const float* __restrict__ X,
    float* Out)
{
    const int tid = threadIdx.x;
    const int wv = tid >> 6, ln = tid & 63;
    const int m = ln & 15, part = ln >> 4;
    const long rb = (long)blockIdx.x * 64 + wv * 16;

    bf16x8 a[4];
    const float* brow = B + (rb + m) * 128 + part * 8;
    #pragma unroll
    for (int kc = 0; kc < 4; ++kc) {
        f32x4 h0 = *reinterpret_cast<const f32x4*>(brow + kc * 32);
        f32x4 h1 = *reinterpret_cast<const f32x4*>(brow + kc * 32 + 4);
        a[kc] = cvt8(h0, h1);
    }
    #pragma unroll
    for (int nt = 0; nt < 8; ++nt) {
        f32x4 acc = (f32x4)(0.0f);
        #pragma unroll
        for (int kc = 0; kc < 4; ++kc) {
            bf16x8 b = *reinterpret_cast<const bf16x8*>(Wfz + ((nt * 4 + kc) * 64 + ln) * 8);
            acc = MFMA(a[kc], b, acc);
        }
        #pragma unroll
        for (int r = 0; r < 4; ++r) {
            long p = rb + part * 4 + r;
            int col = nt * 16 + m;
            float s = 1.f / (1.f + __expf(-acc[r]));
            float av = b2f(A16[p * 128 + col]);
            Out[p * 128 + col] = av * s + X[p * 128 + col];
        }
    }
}

// ======================================================================
// ws: A16 (NPTS*128 bf16) | T1 ((NPTS+1)*64 bf16, sentinel) | Z (778240)
//   ≈ 47.6 MB.
// ======================================================================
extern "C" void kernel_launch(void* const* d_in, const int* in_sizes, int n_in,
                              void* d_out, int out_size, void* d_ws, size_t ws_size,
                              hipStream_t stream)
{
    const float* x   = (const float*)d_in[0];
    const float* W1s = (const float*)d_in[1];
    const float* Wks = (const float*)d_in[2];
    const float* W2s = (const float*)d_in[3];
    const float* Wf  = (const float*)d_in[4];
    const int*   nbr = (const int*)d_in[5];
    float*       out = (float*)d_out;

    uint16_t* A16 = (uint16_t*)d_ws;                       // NPTS*128
    uint16_t* T1  = A16 + (size_t)NPTS * 128;              // (NPTS+1)*64
    uint16_t* Z   = T1 + (size_t)(NPTS + 1) * 64;          // 778240
    const uint16_t* W1z = Z;
    const uint16_t* Wkz = Z + 49152;
    const uint16_t* W2z = Z + 712704;
    const uint16_t* Wfz = Z + 761856;

    k_swz<<<dim3(3040), dim3(256), 0, stream>>>(W1s, Wks, W2s, Wf, Z, T1);

    auto unit = [&](int i, const float* hin, float* houtF, uint16_t* houtB, int obf) {
        k_gemm1<<<dim3(1875), dim3(256), 0, stream>>>(hin, W1z + (size_t)i * 8192, T1);
        k_convg2<<<dim3(1875), dim3(128), 0, stream>>>(T1, Wkz + (size_t)i * 110592,
                                                       W2z + (size_t)i * 8192,
                                                       hin, nbr, houtF, houtB, obf);
    };

    // branch a (h in d_out); unit 2 also emits aRes bf16 -> A16
    unit(0, x,   out, nullptr, 0);
    unit(1, out, out, nullptr, 0);
    unit(2, out, out, A16,     1);
    // branch b (h in d_out, reused)
    unit(3, x,   out, nullptr, 0);
    unit(4, out, out, nullptr, 0);
    unit(5, out, out, nullptr, 0);
    // out = aRes * sigmoid(bRes @ Wf) + x
    k_final<<<dim3(1875), dim3(256), 0, stream>>>(out, Wfz, A16, x, out);
}

// Round 4
// 752.424 us; speedup vs baseline: 1.3486x; 1.3486x over previous
//
#include <hip/hip_runtime.h>
#include <stdint.h>

#define NPTS 120000

typedef __attribute__((ext_vector_type(8))) short bf16x8;   // 8 bf16 = 4 VGPR
typedef __attribute__((ext_vector_type(4))) float f32x4;    // MFMA C/D

__device__ __forceinline__ uint16_t f2b(float f) {
    union { float f; uint32_t i; } v; v.f = f;
    uint32_t x = v.i;
    return (uint16_t)((x + 0x7fffu + ((x >> 16) & 1u)) >> 16);   // RNE
}
__device__ __forceinline__ float b2f(uint16_t u) {
    union { uint32_t i; float f; } v; v.i = ((uint32_t)u) << 16; return v.f;
}
__device__ __forceinline__ bf16x8 cvt8(f32x4 a, f32x4 b) {
    bf16x8 t;
    t[0] = (short)f2b(a[0]); t[1] = (short)f2b(a[1]);
    t[2] = (short)f2b(a[2]); t[3] = (short)f2b(a[3]);
    t[4] = (short)f2b(b[0]); t[5] = (short)f2b(b[1]);
    t[6] = (short)f2b(b[2]); t[7] = (short)f2b(b[3]);
    return t;
}
#define MFMA(a, b, c) __builtin_amdgcn_mfma_f32_16x16x32_bf16((a), (b), (c), 0, 0, 0)

// ======================================================================
// Weight swizzle (validated): f32 [K][N] -> bf16 B-frag order,
// flat ((nt*(K/32)+kc)*64 + l)*8 + j. Also zeroes T1 sentinel row NPTS.
// ======================================================================
__global__ __launch_bounds__(256) void k_swz(
    const float* __restrict__ W1s, const float* __restrict__ Wks,
    const float* __restrict__ W2s, const float* __restrict__ Wf,
    uint16_t* __restrict__ Z, uint16_t* __restrict__ T1z)
{
    if (blockIdx.x == 0 && threadIdx.x < 64)
        T1z[(size_t)NPTS * 64 + threadIdx.x] = 0;   // sentinel zero-row
    int idx = blockIdx.x * 256 + threadIdx.x;
    if (idx >= 778240) return;
    const float* src; int K, N, r;
    if (idx < 49152)       { src = W1s + (idx / 8192) * 8192;           K = 128; N = 64;  r = idx & 8191; }
    else if (idx < 712704) { int t = idx - 49152;  src = Wks + (t >> 12) * 4096; K = 64;  N = 64;  r = t & 4095; }
    else if (idx < 761856) { int t = idx - 712704; src = W2s + (t / 8192) * 8192; K = 64;  N = 128; r = t & 8191; }
    else                   { src = Wf; K = 128; N = 128; r = idx - 761856; }
    int j  = r & 7;
    int l  = (r >> 3) & 63;
    int t2 = r >> 9;
    int KC = K >> 5;
    int kc = t2 % KC;
    int nt = t2 / KC;
    int k  = kc * 32 + (l >> 4) * 8 + j;
    int n  = nt * 16 + (l & 15);
    Z[idx] = f2b(src[k * N + n]);
}

// ======================================================================
// T[p][c] = relu(H[p][:] @ W1[:,c]),  K=128, N=64.  (unchanged)
// ======================================================================
__global__ __launch_bounds__(256) void k_gemm1(
    const float* __restrict__ H, const uint16_t* __restrict__ Wz,
    uint16_t* __restrict__ T)
{
    const int tid = threadIdx.x;
    const int wv = tid >> 6, ln = tid & 63;
    const int m = ln & 15, part = ln >> 4;
    const long rb = (long)blockIdx.x * 64 + wv * 16;

    bf16x8 a[4];
    const float* hrow = H + (rb + m) * 128 + part * 8;
    #pragma unroll
    for (int kc = 0; kc < 4; ++kc) {
        f32x4 h0 = *reinterpret_cast<const f32x4*>(hrow + kc * 32);
        f32x4 h1 = *reinterpret_cast<const f32x4*>(hrow + kc * 32 + 4);
        a[kc] = cvt8(h0, h1);
    }
    #pragma unroll
    for (int nt = 0; nt < 4; ++nt) {
        f32x4 acc = (f32x4)(0.0f);
        #pragma unroll
        for (int kc = 0; kc < 4; ++kc) {
            bf16x8 b = *reinterpret_cast<const bf16x8*>(Wz + ((nt * 4 + kc) * 64 + ln) * 8);
            acc = MFMA(a[kc], b, acc);
        }
        #pragma unroll
        for (int r = 0; r < 4; ++r) {
            float v = acc[r] > 0.f ? acc[r] : 0.f;
            T[(rb + part * 4 + r) * 64 + nt * 16 + m] = f2b(v);
        }
    }
}

// ======================================================================
// Fused conv27 + gemm2 with SPLIT-K ACROSS WAVES (the R0 champion
// structure — R1/R2/R3 restructures all regressed; reverted).
// 48 pts/block, 256 thr (4 waves), 2500 blocks. Wave w owns taps
// k = w, w+4, ...
// ROUND-4 CHANGES (theory: latency-bound, LDS-capped at 3 blocks/CU):
//  (a) pairwise TREE reduce: waves 1,3 spill f32; waves 0,2 add their
//      pair; wave 2 respills pair-sum; wave 0 finishes. Exact f32.
//      red shrinks 36.9 KB -> 25.5 KB => LDS 49.0 -> 38.2 KB
//      => 4 blocks/CU (16 waves/CU), occupancy 28% -> ~37%.
//  (b) red row stride 64 -> 68 floats: spill was a 4-way bank conflict
//      (part lanes stride 256 f32), now 2-way (free).
//  (c) snbr pre-scaled <<6 (element offset) to trim gather addr VALU.
// LDS: snbr 5184 + red 26112 + sc2 6912 = 38208 B.
// In-place safe Hout==Hin (block owns its 48 rows; reads precede writes).
// ======================================================================
__global__ __launch_bounds__(256) void k_convg2(
    const uint16_t* __restrict__ T,     // [(NPTS+1)][64] bf16, row NPTS = 0
    const uint16_t* __restrict__ Wkz,   // 27 swizzled 64x64 (4096 each)
    const uint16_t* __restrict__ W2z,   // swizzled 64x128
    const float* Hin,                   // may alias Hout
    const int* __restrict__ nbr,
    float* HoutF, uint16_t* __restrict__ HoutB, int out_bf16)
{
    __shared__ int snbr[27 * 48];                       // 5184 B
    __shared__ __align__(16) float red[2 * 3264];       // 26112 B (stride-68 rows)
    __shared__ __align__(16) uint16_t sc2[48 * 72];     // 6912 B
    const int tid = threadIdx.x;
    const int wv = tid >> 6, ln = tid & 63;
    const int mrow = ln & 15, part = ln >> 4;
    const long bb = (long)blockIdx.x * 48;

    for (int i = tid; i < 1296; i += 256) {
        int lp = i / 27, kk = i - lp * 27;
        int n = nbr[(bb + lp) * 27 + kk];
        snbr[kk * 48 + lp] = ((n < 0) ? NPTS : n) << 6;   // pre-scaled elem offset
    }
    __syncthreads();

    f32x4 acc[3][4];
    #pragma unroll
    for (int mm = 0; mm < 3; ++mm)
        #pragma unroll
        for (int nt = 0; nt < 4; ++nt) acc[mm][nt] = (f32x4)(0.0f);

    for (int k = wv; k < 27; k += 4) {
        bf16x8 A[3][2];
        #pragma unroll
        for (int mm = 0; mm < 3; ++mm) {
            long r0 = (long)snbr[k * 48 + mm * 16 + mrow];
            A[mm][0] = *reinterpret_cast<const bf16x8*>(T + r0 + part * 8);
            A[mm][1] = *reinterpret_cast<const bf16x8*>(T + r0 + 32 + part * 8);
        }
        const uint16_t* wb = Wkz + k * 4096;
        bf16x8 B[8];
        #pragma unroll
        for (int i = 0; i < 8; ++i)
            B[i] = *reinterpret_cast<const bf16x8*>(wb + (i * 64 + ln) * 8);
        #pragma unroll
        for (int nt = 0; nt < 4; ++nt)
            #pragma unroll
            for (int mm = 0; mm < 3; ++mm) {
                acc[mm][nt] = MFMA(A[mm][0], B[nt * 2 + 0], acc[mm][nt]);
                acc[mm][nt] = MFMA(A[mm][1], B[nt * 2 + 1], acc[mm][nt]);
            }
    }

    // ---- pairwise tree reduce (exact f32), 25.5 KB instead of 36.9 ----
    // waves 1,3 spill
    if (wv & 1) {
        float* buf = &red[(wv >> 1) * 3264];
        #pragma unroll
        for (int mm = 0; mm < 3; ++mm)
            #pragma unroll
            for (int nt = 0; nt < 4; ++nt)
                #pragma unroll
                for (int r = 0; r < 4; ++r)
                    buf[(mm * 16 + part * 4 + r) * 68 + nt * 16 + mrow] = acc[mm][nt][r];
    }
    __syncthreads();
    // waves 0,2 absorb their partner's partial
    if (!(wv & 1)) {
        const float* buf = &red[(wv >> 1) * 3264];
        #pragma unroll
        for (int mm = 0; mm < 3; ++mm)
            #pragma unroll
            for (int nt = 0; nt < 4; ++nt)
                #pragma unroll
                for (int r = 0; r < 4; ++r)
                    acc[mm][nt][r] += buf[(mm * 16 + part * 4 + r) * 68 + nt * 16 + mrow];
    }
    __syncthreads();
    // wave 2 respills its pair-sum into slot 0
    if (wv == 2) {
        #pragma unroll
        for (int mm = 0; mm < 3; ++mm)
            #pragma unroll
            for (int nt = 0; nt < 4; ++nt)
                #pragma unroll
                for (int r = 0; r < 4; ++r)
                    red[(mm * 16 + part * 4 + r) * 68 + nt * 16 + mrow] = acc[mm][nt][r];
    }
    __syncthreads();
    // wave 0 finishes: total = own-pair + wave2-pair, relu -> sc2 (bf16)
    if (wv == 0) {
        #pragma unroll
        for (int mm = 0; mm < 3; ++mm)
            #pragma unroll
            for (int nt = 0; nt < 4; ++nt)
                #pragma unroll
                for (int r = 0; r < 4; ++r) {
                    float v = acc[mm][nt][r]
                            + red[(mm * 16 + part * 4 + r) * 68 + nt * 16 + mrow];
                    v = v > 0.f ? v : 0.f;
                    sc2[(mm * 16 + part * 4 + r) * 72 + nt * 16 + mrow] = f2b(v);
                }
    }
    __syncthreads();

    // gemm2: K=64, N=128 split as 2 N-tiles per wave (nt = wv*2 + j)
    bf16x8 a2[3][2];
    #pragma unroll
    for (int mm = 0; mm < 3; ++mm) {
        const uint16_t* crow = sc2 + (mm * 16 + mrow) * 72;
        a2[mm][0] = *reinterpret_cast<const bf16x8*>(crow + part * 8);
        a2[mm][1] = *reinterpret_cast<const bf16x8*>(crow + 32 + part * 8);
    }
    f32x4 acc2[3][2];
    #pragma unroll
    for (int mm = 0; mm < 3; ++mm)
        #pragma unroll
        for (int j = 0; j < 2; ++j) acc2[mm][j] = (f32x4)(0.0f);
    #pragma unroll
    for (int j = 0; j < 2; ++j) {
        int nt = wv * 2 + j;
        bf16x8 b0 = *reinterpret_cast<const bf16x8*>(W2z + ((nt * 2 + 0) * 64 + ln) * 8);
        bf16x8 b1 = *reinterpret_cast<const bf16x8*>(W2z + ((nt * 2 + 1) * 64 + ln) * 8);
        #pragma unroll
        for (int mm = 0; mm < 3; ++mm) {
            acc2[mm][j] = MFMA(a2[mm][0], b0, acc2[mm][j]);
            acc2[mm][j] = MFMA(a2[mm][1], b1, acc2[mm][j]);
        }
    }
    if (out_bf16) {
        #pragma unroll
        for (int mm = 0; mm < 3; ++mm)
            #pragma unroll
            for (int j = 0; j < 2; ++j)
                #pragma unroll
                for (int r = 0; r < 4; ++r) {
                    long p = bb + mm * 16 + part * 4 + r;
                    int col = (wv * 2 + j) * 16 + mrow;
                    float v = acc2[mm][j][r] + Hin[p * 128 + col];
                    v = v > 0.f ? v : 0.f;
                    HoutB[p * 128 + col] = f2b(v);
                }
    } else {
        #pragma unroll
        for (int mm = 0; mm < 3; ++mm)
            #pragma unroll
            for (int j = 0; j < 2; ++j)
                #pragma unroll
                for (int r = 0; r < 4; ++r) {
                    long p = bb + mm * 16 + part * 4 + r;
                    int col = (wv * 2 + j) * 16 + mrow;
                    float v = acc2[mm][j][r] + Hin[p * 128 + col];
                    HoutF[p * 128 + col] = v > 0.f ? v : 0.f;
                }
    }
}

// ======================================================================
// Out[p][c] = A[p][c] * sigmoid( B[p][:] @ Wf[:,c] ) + X[p][c]
// (unchanged; in-place safe Out==B)
// ======================================================================
__global__ __launch_bounds__(256) void k_final(
    const float* B, const uint16_t* __restrict__ Wfz,
    const uint16_t* __restrict__ A16, const float* __restrict__ X,
    float* Out)
{
    const int tid = threadIdx.x;
    const int wv = tid >> 6, ln = tid & 63;
    const int m = ln & 15, part = ln >> 4;
    const long rb = (long)blockIdx.x * 64 + wv * 16;

    bf16x8 a[4];
    const float* brow = B + (rb + m) * 128 + part * 8;
    #pragma unroll
    for (int kc = 0; kc < 4; ++kc) {
        f32x4 h0 = *reinterpret_cast<const f32x4*>(brow + kc * 32);
        f32x4 h1 = *reinterpret_cast<const f32x4*>(brow + kc * 32 + 4);
        a[kc] = cvt8(h0, h1);
    }
    #pragma unroll
    for (int nt = 0; nt < 8; ++nt) {
        f32x4 acc = (f32x4)(0.0f);
        #pragma unroll
        for (int kc = 0; kc < 4; ++kc) {
            bf16x8 b = *reinterpret_cast<const bf16x8*>(Wfz + ((nt * 4 + kc) * 64 + ln) * 8);
            acc = MFMA(a[kc], b, acc);
        }
        #pragma unroll
        for (int r = 0; r < 4; ++r) {
            long p = rb + part * 4 + r;
            int col = nt * 16 + m;
            float s = 1.f / (1.f + __expf(-acc[r]));
            float av = b2f(A16[p * 128 + col]);
            Out[p * 128 + col] = av * s + X[p * 128 + col];
        }
    }
}

// ======================================================================
// ws: A16 (NPTS*128 bf16) | T1 ((NPTS+1)*64 bf16, sentinel) | Z (778240)
//   ≈ 47.6 MB.
// ======================================================================
extern "C" void kernel_launch(void* const* d_in, const int* in_sizes, int n_in,
                              void* d_out, int out_size, void* d_ws, size_t ws_size,
                              hipStream_t stream)
{
    const float* x   = (const float*)d_in[0];
    const float* W1s = (const float*)d_in[1];
    const float* Wks = (const float*)d_in[2];
    const float* W2s = (const float*)d_in[3];
    const float* Wf  = (const float*)d_in[4];
    const int*   nbr = (const int*)d_in[5];
    float*       out = (float*)d_out;

    uint16_t* A16 = (uint16_t*)d_ws;                       // NPTS*128
    uint16_t* T1  = A16 + (size_t)NPTS * 128;              // (NPTS+1)*64
    uint16_t* Z   = T1 + (size_t)(NPTS + 1) * 64;          // 778240
    const uint16_t* W1z = Z;
    const uint16_t* Wkz = Z + 49152;
    const uint16_t* W2z = Z + 712704;
    const uint16_t* Wfz = Z + 761856;

    k_swz<<<dim3(3040), dim3(256), 0, stream>>>(W1s, Wks, W2s, Wf, Z, T1);

    auto unit = [&](int i, const float* hin, float* houtF, uint16_t* houtB, int obf) {
        k_gemm1<<<dim3(1875), dim3(256), 0, stream>>>(hin, W1z + (size_t)i * 8192, T1);
        k_convg2<<<dim3(2500), dim3(256), 0, stream>>>(T1, Wkz + (size_t)i * 110592,
                                                       W2z + (size_t)i * 8192,
                                                       hin, nbr, houtF, houtB, obf);
    };

    // branch a (h in d_out); unit 2 also emits aRes bf16 -> A16
    unit(0, x,   out, nullptr, 0);
    unit(1, out, out, nullptr, 0);
    unit(2, out, out, A16,     1);
    // branch b (h in d_out, reused)
    unit(3, x,   out, nullptr, 0);
    unit(4, out, out, nullptr, 0);
    unit(5, out, out, nullptr, 0);
    // out = aRes * sigmoid(bRes @ Wf) + x
    k_final<<<dim3(1875), dim3(256), 0, stream>>>(out, Wfz, A16, x, out);
}

// Round 5
// 731.338 us; speedup vs baseline: 1.3875x; 1.0288x over previous
//
#include <hip/hip_runtime.h>
#include <stdint.h>

#define NPTS 120000

typedef __attribute__((ext_vector_type(8))) short bf16x8;   // 8 bf16 = 4 VGPR
typedef __attribute__((ext_vector_type(4))) float f32x4;    // MFMA C/D

__device__ __forceinline__ uint16_t f2b(float f) {
    union { float f; uint32_t i; } v; v.f = f;
    uint32_t x = v.i;
    return (uint16_t)((x + 0x7fffu + ((x >> 16) & 1u)) >> 16);   // RNE
}
__device__ __forceinline__ float b2f(uint16_t u) {
    union { uint32_t i; float f; } v; v.i = ((uint32_t)u) << 16; return v.f;
}
__device__ __forceinline__ bf16x8 cvt8(f32x4 a, f32x4 b) {
    bf16x8 t;
    t[0] = (short)f2b(a[0]); t[1] = (short)f2b(a[1]);
    t[2] = (short)f2b(a[2]); t[3] = (short)f2b(a[3]);
    t[4] = (short)f2b(b[0]); t[5] = (short)f2b(b[1]);
    t[6] = (short)f2b(b[2]); t[7] = (short)f2b(b[3]);
    return t;
}
#define MFMA(a, b, c) __builtin_amdgcn_mfma_f32_16x16x32_bf16((a), (b), (c), 0, 0, 0)

// ======================================================================
// Weight swizzle (validated): f32 [K][N] -> bf16 B-frag order,
// flat ((nt*(K/32)+kc)*64 + l)*8 + j. Zeroes sentinel row of BOTH T bufs.
// ======================================================================
__global__ __launch_bounds__(256) void k_swz(
    const float* __restrict__ W1s, const float* __restrict__ Wks,
    const float* __restrict__ W2s, const float* __restrict__ Wf,
    uint16_t* __restrict__ Z, uint16_t* __restrict__ T1z,
    uint16_t* __restrict__ T2z)
{
    if (blockIdx.x == 0) {
        if (threadIdx.x < 64)
            T1z[(size_t)NPTS * 64 + threadIdx.x] = 0;
        else if (threadIdx.x < 128 && T2z)
            T2z[(size_t)NPTS * 64 + (threadIdx.x - 64)] = 0;
    }
    int idx = blockIdx.x * 256 + threadIdx.x;
    if (idx >= 778240) return;
    const float* src; int K, N, r;
    if (idx < 49152)       { src = W1s + (idx / 8192) * 8192;           K = 128; N = 64;  r = idx & 8191; }
    else if (idx < 712704) { int t = idx - 49152;  src = Wks + (t >> 12) * 4096; K = 64;  N = 64;  r = t & 4095; }
    else if (idx < 761856) { int t = idx - 712704; src = W2s + (t / 8192) * 8192; K = 64;  N = 128; r = t & 8191; }
    else                   { src = Wf; K = 128; N = 128; r = idx - 761856; }
    int j  = r & 7;
    int l  = (r >> 3) & 63;
    int t2 = r >> 9;
    int KC = K >> 5;
    int kc = t2 % KC;
    int nt = t2 / KC;
    int k  = kc * 32 + (l >> 4) * 8 + j;
    int n  = nt * 16 + (l & 15);
    Z[idx] = f2b(src[k * N + n]);
}

// ======================================================================
// T[p][c] = relu(H[p][:] @ W1[:,c]),  K=128, N=64.  (unchanged; used
// once for unit 0 in fused mode, 6x in fallback mode)
// ======================================================================
__global__ __launch_bounds__(256) void k_gemm1(
    const float* __restrict__ H, const uint16_t* __restrict__ Wz,
    uint16_t* __restrict__ T)
{
    const int tid = threadIdx.x;
    const int wv = tid >> 6, ln = tid & 63;
    const int m = ln & 15, part = ln >> 4;
    const long rb = (long)blockIdx.x * 64 + wv * 16;

    bf16x8 a[4];
    const float* hrow = H + (rb + m) * 128 + part * 8;
    #pragma unroll
    for (int kc = 0; kc < 4; ++kc) {
        f32x4 h0 = *reinterpret_cast<const f32x4*>(hrow + kc * 32);
        f32x4 h1 = *reinterpret_cast<const f32x4*>(hrow + kc * 32 + 4);
        a[kc] = cvt8(h0, h1);
    }
    #pragma unroll
    for (int nt = 0; nt < 4; ++nt) {
        f32x4 acc = (f32x4)(0.0f);
        #pragma unroll
        for (int kc = 0; kc < 4; ++kc) {
            bf16x8 b = *reinterpret_cast<const bf16x8*>(Wz + ((nt * 4 + kc) * 64 + ln) * 8);
            acc = MFMA(a[kc], b, acc);
        }
        #pragma unroll
        for (int r = 0; r < 4; ++r) {
            float v = acc[r] > 0.f ? acc[r] : 0.f;
            T[(rb + part * 4 + r) * 64 + nt * 16 + m] = f2b(v);
        }
    }
}

// ======================================================================
// Fused conv27 + gemm2 — conv core + reduce is BIT-EXACT R0 (the 95.6us
// champion; R1-R4 alternatives all regressed). ROUND-5 adds EPILOGUE
// FUSION (the conv plateau is memory-system-bound; the win is removing
// the surrounding redundant dispatches/traffic):
//   mode 0: Hout=relu(acc2+Hin) -> HoutF (f32) AND sH (bf16 LDS, aliases
//           the dead 36.9KB red buffer, stride 136 = conflict-free b128);
//           then fused NEXT-LAYER gemm1: Tn = relu(sH @ Wn). Removes a
//           standalone k_gemm1 (61MB H re-read + launch).
//   mode 1: Hout -> A16 bf16 only (unit 2, as before) + fused gemm1 of
//           the OTHER branch's start: Tn = relu(bf16(Xg) @ Wn).
//   mode 2: (unit 5) no global Hout; Out = b2f(A16g)*sigmoid(sH@Wn) + Xg.
//           Removes k_final entirely (61MB read + 61MB write + launch).
// All rounding points identical to the standalone kernels -> absmax
// must be unchanged. T double-buffered (Tn != T) to avoid cross-block
// races. LDS: snbr 5184 + red 36864 + sc2 6912 = 48960 (3 blocks/CU).
// ======================================================================
__global__ __launch_bounds__(256) void k_convg2(
    const uint16_t* __restrict__ T,     // [(NPTS+1)][64] bf16, row NPTS = 0
    const uint16_t* __restrict__ Wkz,   // 27 swizzled 64x64 (4096 each)
    const uint16_t* __restrict__ W2z,   // swizzled 64x128
    const float* Hin,                   // may alias HoutF/OutF
    const int* __restrict__ nbr,
    float* HoutF,                       // mode 0
    uint16_t* __restrict__ HoutB,       // mode 1 (A16)
    const uint16_t* __restrict__ Wn,    // fused panel: W1-next (m0/1) / Wf (m2)
    uint16_t* __restrict__ Tn,          // fused gemm1 dest (m0/1; may be null)
    const float* __restrict__ Xg,       // x (m1 gemm1 source / m2 final add)
    const uint16_t* __restrict__ A16g,  // aRes (m2)
    float* __restrict__ OutF,           // final out (m2)
    int mode)
{
    __shared__ int snbr[27 * 48];                       // 5184 B
    __shared__ __align__(16) float red[3 * 3072];       // 36864 B (waves 1..3 partials)
    __shared__ __align__(16) uint16_t sc2[48 * 72];     // 6912 B
    const int tid = threadIdx.x;
    const int wv = tid >> 6, ln = tid & 63;
    const int mrow = ln & 15, part = ln >> 4;
    const long bb = (long)blockIdx.x * 48;

    for (int i = tid; i < 1296; i += 256) {
        int lp = i / 27, kk = i - lp * 27;
        int n = nbr[(bb + lp) * 27 + kk];
        snbr[kk * 48 + lp] = (n < 0) ? NPTS : n;
    }
    __syncthreads();

    f32x4 acc[3][4];
    #pragma unroll
    for (int mm = 0; mm < 3; ++mm)
        #pragma unroll
        for (int nt = 0; nt < 4; ++nt) acc[mm][nt] = (f32x4)(0.0f);

    for (int k = wv; k < 27; k += 4) {
        bf16x8 A[3][2];
        #pragma unroll
        for (int mm = 0; mm < 3; ++mm) {
            long r0 = (long)snbr[k * 48 + mm * 16 + mrow] * 64;
            A[mm][0] = *reinterpret_cast<const bf16x8*>(T + r0 + part * 8);
            A[mm][1] = *reinterpret_cast<const bf16x8*>(T + r0 + 32 + part * 8);
        }
        const uint16_t* wb = Wkz + k * 4096;
        bf16x8 B[8];
        #pragma unroll
        for (int i = 0; i < 8; ++i)
            B[i] = *reinterpret_cast<const bf16x8*>(wb + (i * 64 + ln) * 8);
        #pragma unroll
        for (int nt = 0; nt < 4; ++nt)
            #pragma unroll
            for (int mm = 0; mm < 3; ++mm) {
                acc[mm][nt] = MFMA(A[mm][0], B[nt * 2 + 0], acc[mm][nt]);
                acc[mm][nt] = MFMA(A[mm][1], B[nt * 2 + 1], acc[mm][nt]);
            }
    }

    // waves 1..3 spill partials; wave 0 reduces + relu -> sc2 (bf16)
    if (wv > 0) {
        float* buf = &red[(wv - 1) * 3072];
        #pragma unroll
        for (int mm = 0; mm < 3; ++mm)
            #pragma unroll
            for (int nt = 0; nt < 4; ++nt)
                #pragma unroll
                for (int r = 0; r < 4; ++r)
                    buf[(mm * 16 + part * 4 + r) * 64 + nt * 16 + mrow] = acc[mm][nt][r];
    }
    __syncthreads();
    if (wv == 0) {
        #pragma unroll
        for (int mm = 0; mm < 3; ++mm)
            #pragma unroll
            for (int nt = 0; nt < 4; ++nt)
                #pragma unroll
                for (int r = 0; r < 4; ++r) {
                    int idx = (mm * 16 + part * 4 + r) * 64 + nt * 16 + mrow;
                    float v = acc[mm][nt][r] + red[idx] + red[3072 + idx] + red[6144 + idx];
                    v = v > 0.f ? v : 0.f;
                    sc2[(mm * 16 + part * 4 + r) * 72 + nt * 16 + mrow] = f2b(v);
                }
    }
    __syncthreads();

    // gemm2: K=64, N=128 split as 2 N-tiles per wave (nt = wv*2 + j)
    bf16x8 a2[3][2];
    #pragma unroll
    for (int mm = 0; mm < 3; ++mm) {
        const uint16_t* crow = sc2 + (mm * 16 + mrow) * 72;
        a2[mm][0] = *reinterpret_cast<const bf16x8*>(crow + part * 8);
        a2[mm][1] = *reinterpret_cast<const bf16x8*>(crow + 32 + part * 8);
    }
    f32x4 acc2[3][2];
    #pragma unroll
    for (int mm = 0; mm < 3; ++mm)
        #pragma unroll
        for (int j = 0; j < 2; ++j) acc2[mm][j] = (f32x4)(0.0f);
    #pragma unroll
    for (int j = 0; j < 2; ++j) {
        int nt = wv * 2 + j;
        bf16x8 b0 = *reinterpret_cast<const bf16x8*>(W2z + ((nt * 2 + 0) * 64 + ln) * 8);
        bf16x8 b1 = *reinterpret_cast<const bf16x8*>(W2z + ((nt * 2 + 1) * 64 + ln) * 8);
        #pragma unroll
        for (int mm = 0; mm < 3; ++mm) {
            acc2[mm][j] = MFMA(a2[mm][0], b0, acc2[mm][j]);
            acc2[mm][j] = MFMA(a2[mm][1], b1, acc2[mm][j]);
        }
    }

    // ---------------- epilogue by mode ----------------
    uint16_t* sH = (uint16_t*)red;   // alias: 48 rows x 136 shorts = 13056 B

    if (mode == 0) {
        // f32 residual out + bf16 copy into LDS for the fused gemm1
        #pragma unroll
        for (int mm = 0; mm < 3; ++mm)
            #pragma unroll
            for (int j = 0; j < 2; ++j)
                #pragma unroll
                for (int r = 0; r < 4; ++r) {
                    int lr = mm * 16 + part * 4 + r;
                    long p = bb + lr;
                    int col = (wv * 2 + j) * 16 + mrow;
                    float v = acc2[mm][j][r] + Hin[p * 128 + col];
                    v = v > 0.f ? v : 0.f;
                    HoutF[p * 128 + col] = v;
                    sH[lr * 136 + col] = f2b(v);
                }
        if (Tn) {
            __syncthreads();
            // fused gemm1: Tn[p] = relu(sH[p] @ Wn), wave owns n-tile wv
            f32x4 t1a[3] = { (f32x4)(0.f), (f32x4)(0.f), (f32x4)(0.f) };
            #pragma unroll
            for (int kc = 0; kc < 4; ++kc) {
                bf16x8 b = *reinterpret_cast<const bf16x8*>(Wn + ((wv * 4 + kc) * 64 + ln) * 8);
                #pragma unroll
                for (int mm = 0; mm < 3; ++mm) {
                    bf16x8 a = *reinterpret_cast<const bf16x8*>(
                        sH + (mm * 16 + mrow) * 136 + kc * 32 + part * 8);
                    t1a[mm] = MFMA(a, b, t1a[mm]);
                }
            }
            #pragma unroll
            for (int mm = 0; mm < 3; ++mm)
                #pragma unroll
                for (int r = 0; r < 4; ++r) {
                    float v = t1a[mm][r]; v = v > 0.f ? v : 0.f;
                    Tn[(bb + mm * 16 + part * 4 + r) * 64 + wv * 16 + mrow] = f2b(v);
                }
        }
    } else if (mode == 1) {
        // bf16 aRes out (unit 2)
        #pragma unroll
        for (int mm = 0; mm < 3; ++mm)
            #pragma unroll
            for (int j = 0; j < 2; ++j)
                #pragma unroll
                for (int r = 0; r < 4; ++r) {
                    long p = bb + mm * 16 + part * 4 + r;
                    int col = (wv * 2 + j) * 16 + mrow;
                    float v = acc2[mm][j][r] + Hin[p * 128 + col];
                    v = v > 0.f ? v : 0.f;
                    HoutB[p * 128 + col] = f2b(v);
                }
        if (Tn) {
            // fused gemm1 of the other branch's start: Tn = relu(bf16(Xg) @ Wn)
            f32x4 t1a[3] = { (f32x4)(0.f), (f32x4)(0.f), (f32x4)(0.f) };
            #pragma unroll
            for (int kc = 0; kc < 4; ++kc) {
                bf16x8 b = *reinterpret_cast<const bf16x8*>(Wn + ((wv * 4 + kc) * 64 + ln) * 8);
                #pragma unroll
                for (int mm = 0; mm < 3; ++mm) {
                    const float* xr = Xg + (bb + mm * 16 + mrow) * 128 + kc * 32 + part * 8;
                    f32x4 h0 = *reinterpret_cast<const f32x4*>(xr);
                    f32x4 h1 = *reinterpret_cast<const f32x4*>(xr + 4);
                    t1a[mm] = MFMA(cvt8(h0, h1), b, t1a[mm]);
                }
            }
            #pragma unroll
            for (int mm = 0; mm < 3; ++mm)
                #pragma unroll
                for (int r = 0; r < 4; ++r) {
                    float v = t1a[mm][r]; v = v > 0.f ? v : 0.f;
                    Tn[(bb + mm * 16 + part * 4 + r) * 64 + wv * 16 + mrow] = f2b(v);
                }
        }
    } else {
        // mode 2 (unit 5): fused final. No global Hout write.
        #pragma unroll
        for (int mm = 0; mm < 3; ++mm)
            #pragma unroll
            for (int j = 0; j < 2; ++j)
                #pragma unroll
                for (int r = 0; r < 4; ++r) {
                    int lr = mm * 16 + part * 4 + r;
                    long p = bb + lr;
                    int col = (wv * 2 + j) * 16 + mrow;
                    float v = acc2[mm][j][r] + Hin[p * 128 + col];
                    v = v > 0.f ? v : 0.f;
                    sH[lr * 136 + col] = f2b(v);
                }
        __syncthreads();
        bf16x8 af[3][4];
        #pragma unroll
        for (int mm = 0; mm < 3; ++mm)
            #pragma unroll
            for (int kc = 0; kc < 4; ++kc)
                af[mm][kc] = *reinterpret_cast<const bf16x8*>(
                    sH + (mm * 16 + mrow) * 136 + kc * 32 + part * 8);
        #pragma unroll
        for (int j = 0; j < 2; ++j) {
            int nt = wv * 2 + j;
            f32x4 fa[3] = { (f32x4)(0.f), (f32x4)(0.f), (f32x4)(0.f) };
            #pragma unroll
            for (int kc = 0; kc < 4; ++kc) {
                bf16x8 b = *reinterpret_cast<const bf16x8*>(Wn + ((nt * 4 + kc) * 64 + ln) * 8);
                #pragma unroll
                for (int mm = 0; mm < 3; ++mm)
                    fa[mm] = MFMA(af[mm][kc], b, fa[mm]);
            }
            #pragma unroll
            for (int mm = 0; mm < 3; ++mm)
                #pragma unroll
                for (int r = 0; r < 4; ++r) {
                    long p = bb + mm * 16 + part * 4 + r;
                    int col = nt * 16 + mrow;
                    float s = 1.f / (1.f + __expf(-fa[mm][r]));
                    OutF[p * 128 + col] = b2f(A16g[p * 128 + col]) * s + Xg[p * 128 + col];
                }
        }
    }
}

// ======================================================================
// Out[p][c] = A[p][c] * sigmoid( B[p][:] @ Wf[:,c] ) + X[p][c]
// (fallback path only)
// ======================================================================
__global__ __launch_bounds__(256) void k_final(
    const float* B, const uint16_t* __restrict__ Wfz,
    const uint16_t* __restrict__ A16, const float* __restrict__ X,
    float* Out)
{
    const int tid = threadIdx.x;
    const int wv = tid >> 6, ln = tid & 63;
    const int m = ln & 15, part = ln >> 4;
    const long rb = (long)blockIdx.x * 64 + wv * 16;

    bf16x8 a[4];
    const float* brow = B + (rb + m) * 128 + part * 8;
    #pragma unroll
    for (int kc = 0; kc < 4; ++kc) {
        f32x4 h0 = *reinterpret_cast<const f32x4*>(brow + kc * 32);
        f32x4 h1 = *reinterpret_cast<const f32x4*>(brow + kc * 32 + 4);
        a[kc] = cvt8(h0, h1);
    }
    #pragma unroll
    for (int nt = 0; nt < 8; ++nt) {
        f32x4 acc = (f32x4)(0.0f);
        #pragma unroll
        for (int kc = 0; kc < 4; ++kc) {
            bf16x8 b = *reinterpret_cast<const bf16x8*>(Wfz + ((nt * 4 + kc) * 64 + ln) * 8);
            acc = MFMA(a[kc], b, acc);
        }
        #pragma unroll
        for (int r = 0; r < 4; ++r) {
            long p = rb + part * 4 + r;
            int col = nt * 16 + m;
            float s = 1.f / (1.f + __expf(-acc[r]));
            float av = b2f(A16[p * 128 + col]);
            Out[p * 128 + col] = av * s + X[p * 128 + col];
        }
    }
}

// ======================================================================
// ws (fused): A16 (NPTS*128) | Ta | Tb ((NPTS+1)*64 each) | Z (778240)
//   = 63.0 MB. Falls back to the single-T R0 sequence (47.6 MB) if
//   ws_size is insufficient.
// ======================================================================
extern "C" void kernel_launch(void* const* d_in, const int* in_sizes, int n_in,
                              void* d_out, int out_size, void* d_ws, size_t ws_size,
                              hipStream_t stream)
{
    const float* x   = (const float*)d_in[0];
    const float* W1s = (const float*)d_in[1];
    const float* Wks = (const float*)d_in[2];
    const float* W2s = (const float*)d_in[3];
    const float* Wf  = (const float*)d_in[4];
    const int*   nbr = (const int*)d_in[5];
    float*       out = (float*)d_out;

    const size_t A16_n = (size_t)NPTS * 128;
    const size_t T_n   = (size_t)(NPTS + 1) * 64;
    const size_t Z_n   = 778240;
    const size_t need2 = (A16_n + 2 * T_n + Z_n) * 2;   // bytes, dual-T

    uint16_t* A16 = (uint16_t*)d_ws;
    uint16_t* Ta  = A16 + A16_n;
    bool dual = ws_size >= need2;
    uint16_t* Tb  = dual ? Ta + T_n : nullptr;
    uint16_t* Z   = dual ? Tb + T_n : Ta + T_n;
    const uint16_t* W1z = Z;
    const uint16_t* Wkz = Z + 49152;
    const uint16_t* W2z = Z + 712704;
    const uint16_t* Wfz = Z + 761856;

    k_swz<<<dim3(3040), dim3(256), 0, stream>>>(W1s, Wks, W2s, Wf, Z, Ta, Tb);

    if (dual) {
        auto conv = [&](int i, const uint16_t* Tc, const float* hin,
                        float* houtF, uint16_t* houtB,
                        const uint16_t* wn, uint16_t* tn,
                        const float* xg, const uint16_t* a16g, float* outF, int mode) {
            k_convg2<<<dim3(2500), dim3(256), 0, stream>>>(
                Tc, Wkz + (size_t)i * 110592, W2z + (size_t)i * 8192,
                hin, nbr, houtF, houtB, wn, tn, xg, a16g, outF, mode);
        };
        k_gemm1<<<dim3(1875), dim3(256), 0, stream>>>(x, W1z, Ta);
        // branch a: conv_i fuses gemm1 of the NEXT unit
        conv(0, Ta, x,   out, nullptr, W1z + 1 * 8192, Tb, nullptr, nullptr, nullptr, 0);
        conv(1, Tb, out, out, nullptr, W1z + 2 * 8192, Ta, nullptr, nullptr, nullptr, 0);
        conv(2, Ta, out, nullptr, A16, W1z + 3 * 8192, Tb, x,       nullptr, nullptr, 1);
        // branch b (unit 3 residual base is x)
        conv(3, Tb, x,   out, nullptr, W1z + 4 * 8192, Ta, nullptr, nullptr, nullptr, 0);
        conv(4, Ta, out, out, nullptr, W1z + 5 * 8192, Tb, nullptr, nullptr, nullptr, 0);
        // unit 5 + final fused: out = b2f(A16)*sigmoid(Hout5@Wf) + x
        conv(5, Tb, out, nullptr, nullptr, Wfz, nullptr, x, A16, out, 2);
    } else {
        // fallback = R0 champion sequence
        auto unit = [&](int i, const float* hin, float* houtF, uint16_t* houtB, int m) {
            k_gemm1<<<dim3(1875), dim3(256), 0, stream>>>(hin, W1z + (size_t)i * 8192, Ta);
            k_convg2<<<dim3(2500), dim3(256), 0, stream>>>(
                Ta, Wkz + (size_t)i * 110592, W2z + (size_t)i * 8192,
                hin, nbr, houtF, houtB, nullptr, nullptr, nullptr, nullptr, nullptr, m);
        };
        unit(0, x,   out, nullptr, 0);
        unit(1, out, out, nullptr, 0);
        unit(2, out, nullptr, A16, 1);
        unit(3, x,   out, nullptr, 0);
        unit(4, out, out, nullptr, 0);
        unit(5, out, out, nullptr, 0);
        k_final<<<dim3(1875), dim3(256), 0, stream>>>(out, Wfz, A16, x, out);
    }
}

// Round 6
// 675.548 us; speedup vs baseline: 1.5020x; 1.0826x over previous
//
#include <hip/hip_runtime.h>
#include <stdint.h>

#define NPTS 120000

typedef __attribute__((ext_vector_type(8))) short bf16x8;   // 8 bf16 = 4 VGPR
typedef __attribute__((ext_vector_type(4))) float f32x4;    // MFMA C/D

__device__ __forceinline__ uint16_t f2b(float f) {
    union { float f; uint32_t i; } v; v.f = f;
    uint32_t x = v.i;
    return (uint16_t)((x + 0x7fffu + ((x >> 16) & 1u)) >> 16);   // RNE
}
__device__ __forceinline__ float b2f(uint16_t u) {
    union { uint32_t i; float f; } v; v.i = ((uint32_t)u) << 16; return v.f;
}
__device__ __forceinline__ bf16x8 cvt8(f32x4 a, f32x4 b) {
    bf16x8 t;
    t[0] = (short)f2b(a[0]); t[1] = (short)f2b(a[1]);
    t[2] = (short)f2b(a[2]); t[3] = (short)f2b(a[3]);
    t[4] = (short)f2b(b[0]); t[5] = (short)f2b(b[1]);
    t[6] = (short)f2b(b[2]); t[7] = (short)f2b(b[3]);
    return t;
}
#define MFMA(a, b, c) __builtin_amdgcn_mfma_f32_16x16x32_bf16((a), (b), (c), 0, 0, 0)

// ======================================================================
// Weight swizzle (validated): f32 [K][N] -> bf16 B-frag order,
// flat ((nt*(K/32)+kc)*64 + l)*8 + j. Also zeroes T sentinel row NPTS.
// ======================================================================
__global__ __launch_bounds__(256) void k_swz(
    const float* __restrict__ W1s, const float* __restrict__ Wks,
    const float* __restrict__ W2s, const float* __restrict__ Wf,
    uint16_t* __restrict__ Z, uint16_t* __restrict__ T1z)
{
    if (blockIdx.x == 0 && threadIdx.x < 64)
        T1z[(size_t)NPTS * 64 + threadIdx.x] = 0;   // sentinel zero-row
    int idx = blockIdx.x * 256 + threadIdx.x;
    if (idx >= 778240) return;
    const float* src; int K, N, r;
    if (idx < 49152)       { src = W1s + (idx / 8192) * 8192;           K = 128; N = 64;  r = idx & 8191; }
    else if (idx < 712704) { int t = idx - 49152;  src = Wks + (t >> 12) * 4096; K = 64;  N = 64;  r = t & 4095; }
    else if (idx < 761856) { int t = idx - 712704; src = W2s + (t / 8192) * 8192; K = 64;  N = 128; r = t & 8191; }
    else                   { src = Wf; K = 128; N = 128; r = idx - 761856; }
    int j  = r & 7;
    int l  = (r >> 3) & 63;
    int t2 = r >> 9;
    int KC = K >> 5;
    int kc = t2 % KC;
    int nt = t2 / KC;
    int k  = kc * 32 + (l >> 4) * 8 + j;
    int n  = nt * 16 + (l & 15);
    Z[idx] = f2b(src[k * N + n]);
}

// ======================================================================
// nbr [NPTS][27] -> nbrT [27][NPTS], sentinel applied (n<0 -> NPTS) and
// pre-scaled <<6 (element offset into T). LDS tile transpose: both the
// global read and the global write are coalesced. One-time ~10 us.
// ======================================================================
__global__ __launch_bounds__(256) void k_nbrT(
    const int* __restrict__ nbr, int* __restrict__ nbrT)
{
    __shared__ int st[27 * 64];
    const int tid = threadIdx.x;
    const long p0 = (long)blockIdx.x * 64;
    for (int i = tid; i < 1728; i += 256) {
        int lp = i / 27, kk = i - lp * 27;
        int n = nbr[p0 * 27 + i];
        st[kk * 64 + lp] = ((n < 0) ? NPTS : n) << 6;
    }
    __syncthreads();
    for (int i = tid; i < 1728; i += 256) {
        int kk = i >> 6, lp = i & 63;
        nbrT[(long)kk * NPTS + p0 + lp] = st[i];
    }
}

// ======================================================================
// T[p][c] = relu(H[p][:] @ W1[:,c]),  K=128, N=64.  (unchanged)
// ======================================================================
__global__ __launch_bounds__(256) void k_gemm1(
    const float* __restrict__ H, const uint16_t* __restrict__ Wz,
    uint16_t* __restrict__ T)
{
    const int tid = threadIdx.x;
    const int wv = tid >> 6, ln = tid & 63;
    const int m = ln & 15, part = ln >> 4;
    const long rb = (long)blockIdx.x * 64 + wv * 16;

    bf16x8 a[4];
    const float* hrow = H + (rb + m) * 128 + part * 8;
    #pragma unroll
    for (int kc = 0; kc < 4; ++kc) {
        f32x4 h0 = *reinterpret_cast<const f32x4*>(hrow + kc * 32);
        f32x4 h1 = *reinterpret_cast<const f32x4*>(hrow + kc * 32 + 4);
        a[kc] = cvt8(h0, h1);
    }
    #pragma unroll
    for (int nt = 0; nt < 4; ++nt) {
        f32x4 acc = (f32x4)(0.0f);
        #pragma unroll
        for (int kc = 0; kc < 4; ++kc) {
            bf16x8 b = *reinterpret_cast<const bf16x8*>(Wz + ((nt * 4 + kc) * 64 + ln) * 8);
            acc = MFMA(a[kc], b, acc);
        }
        #pragma unroll
        for (int r = 0; r < 4; ++r) {
            float v = acc[r] > 0.f ? acc[r] : 0.f;
            T[(rb + part * 4 + r) * 64 + nt * 16 + m] = f2b(v);
        }
    }
}

// ======================================================================
// ROUND-6 conv27+gemm2: SPLIT-M + BLOCK-SHARED LDS WEIGHT PANELS.
// Theory: R0 moved ~1.1 GB through L1/L2 per dispatch (~45 B/cyc/CU =
// request-throughput wall); 540 MB of it was weight panels read once
// per 48 points. This kernel reads each 8-KB tap panel ONCE per 192
// points (reg-staged T14-style into a double-buffered LDS panel shared
// by 4 waves) => weight traffic /4 (540->135 MB). Wave w owns rows
// [bb+48w, +48), all 27 taps, sequential accumulate (R1's validated
// order, absmax 0.0625). No reduction, no red LDS, no snbr: per-tap
// indices come from nbrT (coalesced broadcast loads, depth-1 prefetch).
// MODE 0: Hout f32 = relu(acc2+Hin).  MODE 1: Hout bf16 (A16).
// MODE 2: fused final (unit 5): Out = b2f(A16)*sigmoid(Hres@Wf) + X.
// LDS: panels 16384 + per-wave union 4*6912 (mode2: 4*13056)
//   = 44032 B (3 blk/CU) / 68608 B (2 blk/CU, mode 2 only).
// In-place safe: epilogue reads Hin only at the block's own rows,
// same-lane read-then-write.
// ======================================================================
template<int MODE>
__global__ __launch_bounds__(256, (MODE == 2) ? 2 : 3) void k_conv(
    const uint16_t* __restrict__ T,     // [(NPTS+1)][64] bf16, row NPTS = 0
    const uint16_t* __restrict__ Wkz,   // 27 swizzled 64x64 (4096 each)
    const uint16_t* __restrict__ W2z,   // swizzled 64x128
    const float* Hin,                   // may alias HoutF / OutF
    const int* __restrict__ nbrT,       // [27][NPTS], pre-scaled <<6
    float* HoutF,                       // MODE 0
    uint16_t* __restrict__ HoutB,       // MODE 1
    const uint16_t* __restrict__ Wfz,   // MODE 2
    const uint16_t* __restrict__ A16g,  // MODE 2
    const float* __restrict__ Xg,       // MODE 2
    float* __restrict__ OutF)           // MODE 2
{
    constexpr int SLICE_SH = (MODE == 2) ? 6528 : 3456;   // shorts per wave
    __shared__ __align__(16) uint16_t wkbuf[2][4096];     // 16384 B
    __shared__ __align__(16) uint16_t uni[4][SLICE_SH];
    const int tid = threadIdx.x;
    const int wv = tid >> 6, ln = tid & 63;
    const int mrow = ln & 15, part = ln >> 4, pc8 = part * 8;
    const long bb = (long)blockIdx.x * 192;
    const long wb0 = bb + wv * 48;

    // prologue: stage panel 0 (each wave its 2-KB quarter) + tap-0 idx
    {
        const uint16_t* g = Wkz + wv * 1024 + ln * 8;
        bf16x8 s0 = *reinterpret_cast<const bf16x8*>(g);
        bf16x8 s1 = *reinterpret_cast<const bf16x8*>(g + 512);
        *reinterpret_cast<bf16x8*>(&wkbuf[0][wv * 1024 + ln * 8]) = s0;
        *reinterpret_cast<bf16x8*>(&wkbuf[0][wv * 1024 + 512 + ln * 8]) = s1;
    }
    int idx[3];
    #pragma unroll
    for (int mm = 0; mm < 3; ++mm) idx[mm] = nbrT[wb0 + mm * 16 + mrow];
    __syncthreads();

    f32x4 acc[3][4];
    #pragma unroll
    for (int mm = 0; mm < 3; ++mm)
        #pragma unroll
        for (int nt = 0; nt < 4; ++nt) acc[mm][nt] = (f32x4)(0.0f);

    int cur = 0;
    #pragma unroll 1
    for (int k = 0; k < 27; ++k) {
        // A gathers for tap k (idx prefetched last tap)
        bf16x8 A[3][2];
        #pragma unroll
        for (int mm = 0; mm < 3; ++mm) {
            const uint16_t* s = T + (long)idx[mm] + pc8;
            A[mm][0] = *reinterpret_cast<const bf16x8*>(s);
            A[mm][1] = *reinterpret_cast<const bf16x8*>(s + 32);
        }
        // issue next panel loads + next idx loads (consumed after MFMAs)
        bf16x8 s0, s1;
        if (k < 26) {
            const uint16_t* g = Wkz + (k + 1) * 4096 + wv * 1024 + ln * 8;
            s0 = *reinterpret_cast<const bf16x8*>(g);
            s1 = *reinterpret_cast<const bf16x8*>(g + 512);
            const int* ib = nbrT + (long)(k + 1) * NPTS + wb0;
            #pragma unroll
            for (int mm = 0; mm < 3; ++mm) idx[mm] = ib[mm * 16 + mrow];
        }
        // B frags from the shared LDS panel (stride-1 b128, conflict-free)
        bf16x8 B[8];
        #pragma unroll
        for (int i = 0; i < 8; ++i)
            B[i] = *reinterpret_cast<const bf16x8*>(&wkbuf[cur][i * 512 + ln * 8]);
        #pragma unroll
        for (int nt = 0; nt < 4; ++nt)
            #pragma unroll
            for (int mm = 0; mm < 3; ++mm) {
                acc[mm][nt] = MFMA(A[mm][0], B[nt * 2 + 0], acc[mm][nt]);
                acc[mm][nt] = MFMA(A[mm][1], B[nt * 2 + 1], acc[mm][nt]);
            }
        // write-late: staged panel k+1 into the other buffer
        if (k < 26) {
            *reinterpret_cast<bf16x8*>(&wkbuf[cur ^ 1][wv * 1024 + ln * 8]) = s0;
            *reinterpret_cast<bf16x8*>(&wkbuf[cur ^ 1][wv * 1024 + 512 + ln * 8]) = s1;
        }
        __syncthreads();
        cur ^= 1;
    }

    // per-wave transpose: acc (C-layout) -> sc2 (relu, bf16), stride 72
    uint16_t* sc2 = &uni[wv][0];
    #pragma unroll
    for (int mm = 0; mm < 3; ++mm)
        #pragma unroll
        for (int nt = 0; nt < 4; ++nt)
            #pragma unroll
            for (int r = 0; r < 4; ++r) {
                float v = acc[mm][nt][r];
                v = v > 0.f ? v : 0.f;
                sc2[(mm * 16 + part * 4 + r) * 72 + nt * 16 + mrow] = f2b(v);
            }
    __builtin_amdgcn_wave_barrier();

    bf16x8 a2[3][2];
    #pragma unroll
    for (int mm = 0; mm < 3; ++mm) {
        const uint16_t* crow = sc2 + (mm * 16 + mrow) * 72;
        a2[mm][0] = *reinterpret_cast<const bf16x8*>(crow + pc8);
        a2[mm][1] = *reinterpret_cast<const bf16x8*>(crow + 32 + pc8);
    }
    __builtin_amdgcn_wave_barrier();

    // gemm2: K=64, N=128; wave owns its 48 rows, all 8 n-tiles
    #pragma unroll 2
    for (int nt = 0; nt < 8; ++nt) {
        bf16x8 b0 = *reinterpret_cast<const bf16x8*>(W2z + ((nt * 2 + 0) * 64 + ln) * 8);
        bf16x8 b1 = *reinterpret_cast<const bf16x8*>(W2z + ((nt * 2 + 1) * 64 + ln) * 8);
        f32x4 c[3];
        #pragma unroll
        for (int mm = 0; mm < 3; ++mm) {
            c[mm] = (f32x4)(0.0f);
            c[mm] = MFMA(a2[mm][0], b0, c[mm]);
            c[mm] = MFMA(a2[mm][1], b1, c[mm]);
        }
        const int col = nt * 16 + mrow;
        if (MODE == 0) {
            #pragma unroll
            for (int mm = 0; mm < 3; ++mm)
                #pragma unroll
                for (int r = 0; r < 4; ++r) {
                    long p = wb0 + mm * 16 + part * 4 + r;
                    float v = c[mm][r] + Hin[p * 128 + col];
                    HoutF[p * 128 + col] = v > 0.f ? v : 0.f;
                }
        } else if (MODE == 1) {
            #pragma unroll
            for (int mm = 0; mm < 3; ++mm)
                #pragma unroll
                for (int r = 0; r < 4; ++r) {
                    long p = wb0 + mm * 16 + part * 4 + r;
                    float v = c[mm][r] + Hin[p * 128 + col];
                    v = v > 0.f ? v : 0.f;
                    HoutB[p * 128 + col] = f2b(v);
                }
        } else {
            uint16_t* sH = &uni[wv][0];
            #pragma unroll
            for (int mm = 0; mm < 3; ++mm)
                #pragma unroll
                for (int r = 0; r < 4; ++r) {
                    long p = wb0 + mm * 16 + part * 4 + r;
                    float v = c[mm][r] + Hin[p * 128 + col];
                    v = v > 0.f ? v : 0.f;
                    sH[(mm * 16 + part * 4 + r) * 136 + col] = f2b(v);
                }
        }
    }

    if (MODE == 2) {
        __builtin_amdgcn_wave_barrier();
        const uint16_t* sH = &uni[wv][0];
        bf16x8 af[3][4];
        #pragma unroll
        for (int mm = 0; mm < 3; ++mm)
            #pragma unroll
            for (int kc = 0; kc < 4; ++kc)
                af[mm][kc] = *reinterpret_cast<const bf16x8*>(
                    sH + (mm * 16 + mrow) * 136 + kc * 32 + pc8);
        #pragma unroll 2
        for (int nt = 0; nt < 8; ++nt) {
            f32x4 fa[3] = { (f32x4)(0.f), (f32x4)(0.f), (f32x4)(0.f) };
            #pragma unroll
            for (int kc = 0; kc < 4; ++kc) {
                bf16x8 b = *reinterpret_cast<const bf16x8*>(Wfz + ((nt * 4 + kc) * 64 + ln) * 8);
                #pragma unroll
                for (int mm = 0; mm < 3; ++mm)
                    fa[mm] = MFMA(af[mm][kc], b, fa[mm]);
            }
            const int col = nt * 16 + mrow;
            #pragma unroll
            for (int mm = 0; mm < 3; ++mm)
                #pragma unroll
                for (int r = 0; r < 4; ++r) {
                    long p = wb0 + mm * 16 + part * 4 + r;
                    float s = 1.f / (1.f + __expf(-fa[mm][r]));
                    OutF[p * 128 + col] = b2f(A16g[p * 128 + col]) * s + Xg[p * 128 + col];
                }
        }
    }
}

// ======================================================================
// ws: A16 (NPTS*128 sh) | T ((NPTS+1)*64 sh) | Z (778240 sh)
//     | nbrT (27*NPTS int)  = 60.6 MB  (harness ws proven >= 63 MB, R5)
// ======================================================================
extern "C" void kernel_launch(void* const* d_in, const int* in_sizes, int n_in,
                              void* d_out, int out_size, void* d_ws, size_t ws_size,
                              hipStream_t stream)
{
    const float* x   = (const float*)d_in[0];
    const float* W1s = (const float*)d_in[1];
    const float* Wks = (const float*)d_in[2];
    const float* W2s = (const float*)d_in[3];
    const float* Wf  = (const float*)d_in[4];
    const int*   nbr = (const int*)d_in[5];
    float*       out = (float*)d_out;

    uint16_t* A16 = (uint16_t*)d_ws;                       // NPTS*128
    uint16_t* T1  = A16 + (size_t)NPTS * 128;              // (NPTS+1)*64
    uint16_t* Z   = T1 + (size_t)(NPTS + 1) * 64;          // 778240
    int* nbrT     = (int*)(Z + 778240);                    // 27*NPTS
    const uint16_t* W1z = Z;
    const uint16_t* Wkz = Z + 49152;
    const uint16_t* W2z = Z + 712704;
    const uint16_t* Wfz = Z + 761856;

    k_swz <<<dim3(3040), dim3(256), 0, stream>>>(W1s, Wks, W2s, Wf, Z, T1);
    k_nbrT<<<dim3(1875), dim3(256), 0, stream>>>(nbr, nbrT);

    auto g1 = [&](int i, const float* h) {
        k_gemm1<<<dim3(1875), dim3(256), 0, stream>>>(h, W1z + (size_t)i * 8192, T1);
    };

    // branch a
    g1(0, x);
    k_conv<0><<<dim3(625), dim3(256), 0, stream>>>(T1, Wkz + 0 * 110592, W2z + 0 * 8192,
        x,   nbrT, out, nullptr, nullptr, nullptr, nullptr, nullptr);
    g1(1, out);
    k_conv<0><<<dim3(625), dim3(256), 0, stream>>>(T1, Wkz + 1 * 110592, W2z + 1 * 8192,
        out, nbrT, out, nullptr, nullptr, nullptr, nullptr, nullptr);
    g1(2, out);
    k_conv<1><<<dim3(625), dim3(256), 0, stream>>>(T1, Wkz + 2 * 110592, W2z + 2 * 8192,
        out, nbrT, nullptr, A16, nullptr, nullptr, nullptr, nullptr);
    // branch b
    g1(3, x);
    k_conv<0><<<dim3(625), dim3(256), 0, stream>>>(T1, Wkz + 3 * 110592, W2z + 3 * 8192,
        x,   nbrT, out, nullptr, nullptr, nullptr, nullptr, nullptr);
    g1(4, out);
    k_conv<0><<<dim3(625), dim3(256), 0, stream>>>(T1, Wkz + 4 * 110592, W2z + 4 * 8192,
        out, nbrT, out, nullptr, nullptr, nullptr, nullptr, nullptr);
    g1(5, out);
    // unit 5 + final fused: out = b2f(A16)*sigmoid(Hres5 @ Wf) + x
    k_conv<2><<<dim3(625), dim3(256), 0, stream>>>(T1, Wkz + 5 * 110592, W2z + 5 * 8192,
        out, nbrT, nullptr, nullptr, Wfz, A16, x, out);
}

// Round 7
// 666.808 us; speedup vs baseline: 1.5217x; 1.0131x over previous
//
#include <hip/hip_runtime.h>
#include <stdint.h>

#define NPTS 120000

typedef __attribute__((ext_vector_type(8))) short bf16x8;   // 8 bf16 = 4 VGPR
typedef __attribute__((ext_vector_type(4))) float f32x4;    // MFMA C/D

__device__ __forceinline__ uint16_t f2b(float f) {
    union { float f; uint32_t i; } v; v.f = f;
    uint32_t x = v.i;
    return (uint16_t)((x + 0x7fffu + ((x >> 16) & 1u)) >> 16);   // RNE
}
__device__ __forceinline__ float b2f(uint16_t u) {
    union { uint32_t i; float f; } v; v.i = ((uint32_t)u) << 16; return v.f;
}
__device__ __forceinline__ bf16x8 cvt8(f32x4 a, f32x4 b) {
    bf16x8 t;
    t[0] = (short)f2b(a[0]); t[1] = (short)f2b(a[1]);
    t[2] = (short)f2b(a[2]); t[3] = (short)f2b(a[3]);
    t[4] = (short)f2b(b[0]); t[5] = (short)f2b(b[1]);
    t[6] = (short)f2b(b[2]); t[7] = (short)f2b(b[3]);
    return t;
}
#define MFMA(a, b, c) __builtin_amdgcn_mfma_f32_16x16x32_bf16((a), (b), (c), 0, 0, 0)

// ======================================================================
// Weight swizzle (validated). Zeroes sentinel row of Ta (and Tb if given).
// ======================================================================
__global__ __launch_bounds__(256) void k_swz(
    const float* __restrict__ W1s, const float* __restrict__ Wks,
    const float* __restrict__ W2s, const float* __restrict__ Wf,
    uint16_t* __restrict__ Z, uint16_t* __restrict__ T1z,
    uint16_t* __restrict__ T2z)
{
    if (blockIdx.x == 0) {
        if (threadIdx.x < 64)
            T1z[(size_t)NPTS * 64 + threadIdx.x] = 0;
        else if (threadIdx.x < 128 && T2z)
            T2z[(size_t)NPTS * 64 + (threadIdx.x - 64)] = 0;
    }
    int idx = blockIdx.x * 256 + threadIdx.x;
    if (idx >= 778240) return;
    const float* src; int K, N, r;
    if (idx < 49152)       { src = W1s + (idx / 8192) * 8192;           K = 128; N = 64;  r = idx & 8191; }
    else if (idx < 712704) { int t = idx - 49152;  src = Wks + (t >> 12) * 4096; K = 64;  N = 64;  r = t & 4095; }
    else if (idx < 761856) { int t = idx - 712704; src = W2s + (t / 8192) * 8192; K = 64;  N = 128; r = t & 8191; }
    else                   { src = Wf; K = 128; N = 128; r = idx - 761856; }
    int j  = r & 7;
    int l  = (r >> 3) & 63;
    int t2 = r >> 9;
    int KC = K >> 5;
    int kc = t2 % KC;
    int nt = t2 / KC;
    int k  = kc * 32 + (l >> 4) * 8 + j;
    int n  = nt * 16 + (l & 15);
    Z[idx] = f2b(src[k * N + n]);
}

// ======================================================================
// nbr [NPTS][27] -> nbrT [27][NPTS], sentinel applied, pre-scaled <<6.
// ======================================================================
__global__ __launch_bounds__(256) void k_nbrT(
    const int* __restrict__ nbr, int* __restrict__ nbrT)
{
    __shared__ int st[27 * 64];
    const int tid = threadIdx.x;
    const long p0 = (long)blockIdx.x * 64;
    for (int i = tid; i < 1728; i += 256) {
        int lp = i / 27, kk = i - lp * 27;
        int n = nbr[p0 * 27 + i];
        st[kk * 64 + lp] = ((n < 0) ? NPTS : n) << 6;
    }
    __syncthreads();
    for (int i = tid; i < 1728; i += 256) {
        int kk = i >> 6, lp = i & 63;
        nbrT[(long)kk * NPTS + p0 + lp] = st[i];
    }
}

// ======================================================================
// gemm1 body: T[p][c] = relu(H[p][:] @ W1[:,c]),  K=128, N=64.
// ======================================================================
__device__ __forceinline__ void gemm1_body(
    int b, const float* __restrict__ H, const uint16_t* __restrict__ Wz,
    uint16_t* __restrict__ T)
{
    const int tid = threadIdx.x;
    const int wv = tid >> 6, ln = tid & 63;
    const int m = ln & 15, part = ln >> 4;
    const long rb = (long)b * 64 + wv * 16;

    bf16x8 a[4];
    const float* hrow = H + (rb + m) * 128 + part * 8;
    #pragma unroll
    for (int kc = 0; kc < 4; ++kc) {
        f32x4 h0 = *reinterpret_cast<const f32x4*>(hrow + kc * 32);
        f32x4 h1 = *reinterpret_cast<const f32x4*>(hrow + kc * 32 + 4);
        a[kc] = cvt8(h0, h1);
    }
    #pragma unroll
    for (int nt = 0; nt < 4; ++nt) {
        f32x4 acc = (f32x4)(0.0f);
        #pragma unroll
        for (int kc = 0; kc < 4; ++kc) {
            bf16x8 b8 = *reinterpret_cast<const bf16x8*>(Wz + ((nt * 4 + kc) * 64 + ln) * 8);
            acc = MFMA(a[kc], b8, acc);
        }
        #pragma unroll
        for (int r = 0; r < 4; ++r) {
            float v = acc[r] > 0.f ? acc[r] : 0.f;
            T[(rb + part * 4 + r) * 64 + nt * 16 + m] = f2b(v);
        }
    }
}

__global__ __launch_bounds__(256) void k_gemm1(
    const float* __restrict__ H, const uint16_t* __restrict__ Wz,
    uint16_t* __restrict__ T)
{
    gemm1_body(blockIdx.x, H, Wz, T);
}

// paired: blocks [0,1875) branch a, [1875,3750) branch b
__global__ __launch_bounds__(256) void k_gemm1p(
    const float* __restrict__ HA, const float* __restrict__ HB,
    const uint16_t* __restrict__ WzA, const uint16_t* __restrict__ WzB,
    uint16_t* __restrict__ TA, uint16_t* __restrict__ TB)
{
    int b = blockIdx.x;
    if (b < 1875) gemm1_body(b, HA, WzA, TA);
    else          gemm1_body(b - 1875, HB, WzB, TB);
}

// ======================================================================
// conv27 + gemm2 body (R6 split-M structure, math-identical), ROUND-7:
// depth-1 A-gather ping-pong + depth-2 index prefetch. tap k+1's 6
// gathers issue BEFORE tap k's 24 MFMAs; idx for k+2 loads during tap k.
// VGPR budget: acc 48 + pA/pB 48 + panel stage 8 + idx/addr ~20 ~ 155
// vs cap 170 (launch_bounds 256,3). No sched_barriers (R2 lesson).
// LDS: wkbuf 16384 + uni 27648 = 44032 -> 3 blocks/CU.
// ======================================================================
struct SM {
    uint16_t wkbuf[2][4096];            // double-buffered tap panel
    uint16_t uni[4][3456];              // per-wave sc2 (stride 72)
};

__device__ __forceinline__ void gather6(bf16x8 (&dst)[3][2], const int (&ix)[3],
                                        const uint16_t* __restrict__ T, int pc8)
{
    #pragma unroll
    for (int mm = 0; mm < 3; ++mm) {
        const uint16_t* s = T + (long)ix[mm] + pc8;
        dst[mm][0] = *reinterpret_cast<const bf16x8*>(s);
        dst[mm][1] = *reinterpret_cast<const bf16x8*>(s + 32);
    }
}
__device__ __forceinline__ void ldidx(int (&ix)[3], const int* __restrict__ p, int mrow)
{
    #pragma unroll
    for (int mm = 0; mm < 3; ++mm) ix[mm] = p[mm * 16 + mrow];
}
__device__ __forceinline__ void pload(bf16x8& s0, bf16x8& s1, const uint16_t* __restrict__ g)
{
    s0 = *reinterpret_cast<const bf16x8*>(g);
    s1 = *reinterpret_cast<const bf16x8*>(g + 512);
}
__device__ __forceinline__ void tap24(f32x4 (&acc)[3][4], const bf16x8 (&A)[3][2],
                                      const uint16_t* wk, int ln)
{
    bf16x8 B[8];
    #pragma unroll
    for (int i = 0; i < 8; ++i)
        B[i] = *reinterpret_cast<const bf16x8*>(wk + i * 512 + ln * 8);
    #pragma unroll
    for (int nt = 0; nt < 4; ++nt)
        #pragma unroll
        for (int mm = 0; mm < 3; ++mm) {
            acc[mm][nt] = MFMA(A[mm][0], B[nt * 2 + 0], acc[mm][nt]);
            acc[mm][nt] = MFMA(A[mm][1], B[nt * 2 + 1], acc[mm][nt]);
        }
}

template<int MODE>   // 0: f32 residual out; 1: bf16 residual out (A16)
__device__ __forceinline__ void conv_body(
    SM& sm, int blk,
    const uint16_t* __restrict__ T, const uint16_t* __restrict__ Wkz,
    const uint16_t* __restrict__ W2z, const float* Hin,
    const int* __restrict__ nbrT, float* HoutF, uint16_t* __restrict__ HoutB)
{
    const int tid = threadIdx.x;
    const int wv = tid >> 6, ln = tid & 63;
    const int mrow = ln & 15, part = ln >> 4, pc8 = part * 8;
    const long bb = (long)blk * 192;
    const long wb0 = bb + wv * 48;

    // prologue: panel 0 -> wkbuf[0]; tap0 gathers in flight; tap1 idx in flight
    {
        bf16x8 s0, s1;
        pload(s0, s1, Wkz + wv * 1024 + ln * 8);
        *reinterpret_cast<bf16x8*>(&sm.wkbuf[0][wv * 1024 + ln * 8]) = s0;
        *reinterpret_cast<bf16x8*>(&sm.wkbuf[0][wv * 1024 + 512 + ln * 8]) = s1;
    }
    int ixA[3], ixB[3];
    bf16x8 pA[3][2], pB[3][2];
    ldidx(ixA, nbrT + wb0, mrow);
    gather6(pA, ixA, T, pc8);
    ldidx(ixB, nbrT + (long)NPTS + wb0, mrow);

    f32x4 acc[3][4];
    #pragma unroll
    for (int mm = 0; mm < 3; ++mm)
        #pragma unroll
        for (int nt = 0; nt < 4; ++nt) acc[mm][nt] = (f32x4)(0.0f);
    __syncthreads();

    #pragma unroll 1
    for (int t = 0; t < 26; t += 2) {
        bf16x8 s0, s1;
        // ---- tap t (pA, wkbuf[0]); prefetch tap t+1 data + t+2 idx ----
        gather6(pB, ixB, T, pc8);
        pload(s0, s1, Wkz + (t + 1) * 4096 + wv * 1024 + ln * 8);
        if (t + 2 < 27) ldidx(ixA, nbrT + (long)(t + 2) * NPTS + wb0, mrow);
        tap24(acc, pA, &sm.wkbuf[0][0], ln);
        *reinterpret_cast<bf16x8*>(&sm.wkbuf[1][wv * 1024 + ln * 8]) = s0;
        *reinterpret_cast<bf16x8*>(&sm.wkbuf[1][wv * 1024 + 512 + ln * 8]) = s1;
        __syncthreads();
        // ---- tap t+1 (pB, wkbuf[1]); prefetch tap t+2 data + t+3 idx ----
        if (t + 1 < 26) {
            gather6(pA, ixA, T, pc8);
            pload(s0, s1, Wkz + (t + 2) * 4096 + wv * 1024 + ln * 8);
            if (t + 3 < 27) ldidx(ixB, nbrT + (long)(t + 3) * NPTS + wb0, mrow);
        }
        tap24(acc, pB, &sm.wkbuf[1][0], ln);
        if (t + 1 < 26) {
            *reinterpret_cast<bf16x8*>(&sm.wkbuf[0][wv * 1024 + ln * 8]) = s0;
            *reinterpret_cast<bf16x8*>(&sm.wkbuf[0][wv * 1024 + 512 + ln * 8]) = s1;
        }
        __syncthreads();
    }
    tap24(acc, pA, &sm.wkbuf[0][0], ln);     // tap 26

    // per-wave transpose: acc -> sc2 (relu, bf16), stride 72
    uint16_t* sc2 = &sm.uni[wv][0];
    #pragma unroll
    for (int mm = 0; mm < 3; ++mm)
        #pragma unroll
        for (int nt = 0; nt < 4; ++nt)
            #pragma unroll
            for (int r = 0; r < 4; ++r) {
                float v = acc[mm][nt][r];
                v = v > 0.f ? v : 0.f;
                sc2[(mm * 16 + part * 4 + r) * 72 + nt * 16 + mrow] = f2b(v);
            }
    __builtin_amdgcn_wave_barrier();

    bf16x8 a2[3][2];
    #pragma unroll
    for (int mm = 0; mm < 3; ++mm) {
        const uint16_t* crow = sc2 + (mm * 16 + mrow) * 72;
        a2[mm][0] = *reinterpret_cast<const bf16x8*>(crow + pc8);
        a2[mm][1] = *reinterpret_cast<const bf16x8*>(crow + 32 + pc8);
    }
    __builtin_amdgcn_wave_barrier();

    // gemm2: K=64, N=128; wave owns its 48 rows
    #pragma unroll 2
    for (int nt = 0; nt < 8; ++nt) {
        bf16x8 b0 = *reinterpret_cast<const bf16x8*>(W2z + ((nt * 2 + 0) * 64 + ln) * 8);
        bf16x8 b1 = *reinterpret_cast<const bf16x8*>(W2z + ((nt * 2 + 1) * 64 + ln) * 8);
        f32x4 c[3];
        #pragma unroll
        for (int mm = 0; mm < 3; ++mm) {
            c[mm] = (f32x4)(0.0f);
            c[mm] = MFMA(a2[mm][0], b0, c[mm]);
            c[mm] = MFMA(a2[mm][1], b1, c[mm]);
        }
        const int col = nt * 16 + mrow;
        if (MODE == 0) {
            #pragma unroll
            for (int mm = 0; mm < 3; ++mm)
                #pragma unroll
                for (int r = 0; r < 4; ++r) {
                    long p = wb0 + mm * 16 + part * 4 + r;
                    float v = c[mm][r] + Hin[p * 128 + col];
                    HoutF[p * 128 + col] = v > 0.f ? v : 0.f;
                }
        } else {
            #pragma unroll
            for (int mm = 0; mm < 3; ++mm)
                #pragma unroll
                for (int r = 0; r < 4; ++r) {
                    long p = wb0 + mm * 16 + part * 4 + r;
                    float v = c[mm][r] + Hin[p * 128 + col];
                    v = v > 0.f ? v : 0.f;
                    HoutB[p * 128 + col] = f2b(v);
                }
        }
    }
}

// single-unit (fallback path)
template<int MODE>
__global__ __launch_bounds__(256, 3) void k_conv1(
    const uint16_t* __restrict__ T, const uint16_t* __restrict__ Wkz,
    const uint16_t* __restrict__ W2z, const float* Hin,
    const int* __restrict__ nbrT, float* HoutF, uint16_t* __restrict__ HoutB)
{
    __shared__ SM sm;
    conv_body<MODE>(sm, blockIdx.x, T, Wkz, W2z, Hin, nbrT, HoutF, HoutB);
}

// paired: blocks [0,625) = branch-a unit (MA), [625,1250) = branch-b unit (MB)
template<int MA, int MB>
__global__ __launch_bounds__(256, 3) void k_convp(
    const uint16_t* __restrict__ Ta, const uint16_t* __restrict__ Tb,
    const uint16_t* __restrict__ WkzA, const uint16_t* __restrict__ WkzB,
    const uint16_t* __restrict__ W2zA, const uint16_t* __restrict__ W2zB,
    const float* HinA, const float* HinB,
    const int* __restrict__ nbrT,
    float* HoFA, float* HoFB,
    uint16_t* __restrict__ HoBA, uint16_t* __restrict__ HoBB)
{
    __shared__ SM sm;
    int b = blockIdx.x;
    if (b < 625) conv_body<MA>(sm, b, Ta, WkzA, W2zA, HinA, nbrT, HoFA, HoBA);
    else         conv_body<MB>(sm, b - 625, Tb, WkzB, W2zB, HinB, nbrT, HoFB, HoBB);
}

// ======================================================================
// Out[p][c] = A[p][c] * sigmoid( B[p][:] @ Wf[:,c] ) + X[p][c]
// ======================================================================
__global__ __launch_bounds__(256) void k_final(
    const float* B, const uint16_t* __restrict__ Wfz,
    const uint16_t* __restrict__ A16, const float* __restrict__ X,
    float* Out)
{
    const int tid = threadIdx.x;
    const int wv = tid >> 6, ln = tid & 63;
    const int m = ln & 15, part = ln >> 4;
    const long rb = (long)blockIdx.x * 64 + wv * 16;

    bf16x8 a[4];
    const float* brow = B + (rb + m) * 128 + part * 8;
    #pragma unroll
    for (int kc = 0; kc < 4; ++kc) {
        f32x4 h0 = *reinterpret_cast<const f32x4*>(brow + kc * 32);
        f32x4 h1 = *reinterpret_cast<const f32x4*>(brow + kc * 32 + 4);
        a[kc] = cvt8(h0, h1);
    }
    #pragma unroll
    for (int nt = 0; nt < 8; ++nt) {
        f32x4 acc = (f32x4)(0.0f);
        #pragma unroll
        for (int kc = 0; kc < 4; ++kc) {
            bf16x8 b = *reinterpret_cast<const bf16x8*>(Wfz + ((nt * 4 + kc) * 64 + ln) * 8);
            acc = MFMA(a[kc], b, acc);
        }
        #pragma unroll
        for (int r = 0; r < 4; ++r) {
            long p = rb + part * 4 + r;
            int col = nt * 16 + m;
            float s = 1.f / (1.f + __expf(-acc[r]));
            float av = b2f(A16[p * 128 + col]);
            Out[p * 128 + col] = av * s + X[p * 128 + col];
        }
    }
}

// ======================================================================
// ws (paired): A16 | Ta | Tb | Z | nbrT | Ha  = 137.4 MB.
// Fallback (serial, 60.6 MB) if ws_size is insufficient.
// ======================================================================
extern "C" void kernel_launch(void* const* d_in, const int* in_sizes, int n_in,
                              void* d_out, int out_size, void* d_ws, size_t ws_size,
                              hipStream_t stream)
{
    const float* x   = (const float*)d_in[0];
    const float* W1s = (const float*)d_in[1];
    const float* Wks = (const float*)d_in[2];
    const float* W2s = (const float*)d_in[3];
    const float* Wf  = (const float*)d_in[4];
    const int*   nbr = (const int*)d_in[5];
    float*       out = (float*)d_out;

    const size_t A16_sh = (size_t)NPTS * 128;
    const size_t T_sh   = (size_t)(NPTS + 1) * 64;
    const size_t Z_sh   = 778240;
    const size_t nbrT_i = (size_t)27 * NPTS;

    uint16_t* A16 = (uint16_t*)d_ws;
    uint16_t* Ta  = A16 + A16_sh;
    uint16_t* Tb  = Ta + T_sh;
    uint16_t* Z   = Tb + T_sh;
    int* nbrT     = (int*)(Z + Z_sh);
    float* Ha     = (float*)(nbrT + nbrT_i);
    size_t need_paired = (size_t)((char*)(Ha + A16_sh) - (char*)d_ws);

    if (ws_size >= need_paired) {
        const uint16_t* W1z = Z;
        const uint16_t* Wkz = Z + 49152;
        const uint16_t* W2z = Z + 712704;
        const uint16_t* Wfz = Z + 761856;

        k_swz <<<dim3(3040), dim3(256), 0, stream>>>(W1s, Wks, W2s, Wf, Z, Ta, Tb);
        k_nbrT<<<dim3(1875), dim3(256), 0, stream>>>(nbr, nbrT);

        // pair 0: a0 (x -> Ha), b3 (x -> out)
        k_gemm1p<<<dim3(3750), dim3(256), 0, stream>>>(x, x, W1z, W1z + 3 * 8192, Ta, Tb);
        k_convp<0, 0><<<dim3(1250), dim3(256), 0, stream>>>(
            Ta, Tb, Wkz + 0 * 110592, Wkz + 3 * 110592, W2z + 0 * 8192, W2z + 3 * 8192,
            x, x, nbrT, Ha, out, nullptr, nullptr);
        // pair 1: a1 (Ha -> Ha), b4 (out -> out)
        k_gemm1p<<<dim3(3750), dim3(256), 0, stream>>>(Ha, out, W1z + 1 * 8192, W1z + 4 * 8192, Ta, Tb);
        k_convp<0, 0><<<dim3(1250), dim3(256), 0, stream>>>(
            Ta, Tb, Wkz + 1 * 110592, Wkz + 4 * 110592, W2z + 1 * 8192, W2z + 4 * 8192,
            Ha, out, nbrT, Ha, out, nullptr, nullptr);
        // pair 2: a2 (Ha -> A16 bf16), b5 (out -> out)
        k_gemm1p<<<dim3(3750), dim3(256), 0, stream>>>(Ha, out, W1z + 2 * 8192, W1z + 5 * 8192, Ta, Tb);
        k_convp<1, 0><<<dim3(1250), dim3(256), 0, stream>>>(
            Ta, Tb, Wkz + 2 * 110592, Wkz + 5 * 110592, W2z + 2 * 8192, W2z + 5 * 8192,
            Ha, out, nbrT, nullptr, out, A16, nullptr);
        // final: out = b2f(A16) * sigmoid(out @ Wf) + x
        k_final<<<dim3(1875), dim3(256), 0, stream>>>(out, Wfz, A16, x, out);
    } else {
        // serial fallback (no Tb/Ha): A16 | Ta | Z | nbrT
        uint16_t* Zs   = Ta + T_sh;
        int* nbrTs     = (int*)(Zs + Z_sh);
        const uint16_t* W1z = Zs;
        const uint16_t* Wkz = Zs + 49152;
        const uint16_t* W2z = Zs + 712704;
        const uint16_t* Wfz = Zs + 761856;

        k_swz <<<dim3(3040), dim3(256), 0, stream>>>(W1s, Wks, W2s, Wf, Zs, Ta, nullptr);
        k_nbrT<<<dim3(1875), dim3(256), 0, stream>>>(nbr, nbrTs);

        auto g1 = [&](int i, const float* h) {
            k_gemm1<<<dim3(1875), dim3(256), 0, stream>>>(h, W1z + (size_t)i * 8192, Ta);
        };
        g1(0, x);
        k_conv1<0><<<dim3(625), dim3(256), 0, stream>>>(Ta, Wkz + 0 * 110592, W2z + 0 * 8192, x,   nbrTs, out, nullptr);
        g1(1, out);
        k_conv1<0><<<dim3(625), dim3(256), 0, stream>>>(Ta, Wkz + 1 * 110592, W2z + 1 * 8192, out, nbrTs, out, nullptr);
        g1(2, out);
        k_conv1<1><<<dim3(625), dim3(256), 0, stream>>>(Ta, Wkz + 2 * 110592, W2z + 2 * 8192, out, nbrTs, nullptr, A16);
        g1(3, x);
        k_conv1<0><<<dim3(625), dim3(256), 0, stream>>>(Ta, Wkz + 3 * 110592, W2z + 3 * 8192, x,   nbrTs, out, nullptr);
        g1(4, out);
        k_conv1<0><<<dim3(625), dim3(256), 0, stream>>>(Ta, Wkz + 4 * 110592, W2z + 4 * 8192, out, nbrTs, out, nullptr);
        g1(5, out);
        k_conv1<0><<<dim3(625), dim3(256), 0, stream>>>(Ta, Wkz + 5 * 110592, W2z + 5 * 8192, out, nbrTs, out, nullptr);
        k_final<<<dim3(1875), dim3(256), 0, stream>>>(out, Wfz, A16, x, out);
    }
}